// Round 9
// baseline (102.302 us; speedup 1.0000x reference)
//
#include <hip/hip_runtime.h>
#include <hip/hip_bf16.h>
#include <math.h>

#define NPTS   8192
#define KNN    16
#define G      16
#define NCELL  (G * G * G)
#define NCHUNK 128              // 64-point chunks per cloud
#define NPART  4                // scatter/count partitions per cloud

// Fixed standard-normal quantile boundaries (i/16). Only affect load balance,
// never correctness.
__constant__ float c_B[17] = {
    -1e30f,
    -1.5341205f, -1.1503494f, -0.8871466f, -0.6744898f, -0.4887764f,
    -0.3186394f, -0.1573107f,  0.0f,        0.1573107f,  0.3186394f,
     0.4887764f,  0.6744898f,  0.8871466f,  1.1503494f,  1.5341205f,
     1e30f
};

__device__ __forceinline__ int cellOf(float v) {
    int c = 0;
#pragma unroll
    for (int i = 1; i <= 15; ++i) c += (v >= c_B[i]) ? 1 : 0;
    return c;
}

// spread 4 bits to positions 0,3,6,9
__device__ __forceinline__ int spread3(int v) {
    v = (v | (v << 4)) & 0x0C3;
    v = (v | (v << 2)) & 0x249;
    return v;
}

__device__ __forceinline__ int mortonCell(float px, float py, float pz) {
    return (spread3(cellOf(px)) << 2) | (spread3(cellOf(py)) << 1) | spread3(cellOf(pz));
}

// prev-lane within each 16-lane row (DPP row_shr:1); row-head lanes masked by caller.
__device__ __forceinline__ float dpp_prev_f(float v) {
    int r = __builtin_amdgcn_update_dpp(0, __float_as_int(v), 0x111, 0xF, 0xF, false);
    return __int_as_float(r);
}
__device__ __forceinline__ int dpp_prev_i(int v) {
    return __builtin_amdgcn_update_dpp(0, v, 0x111, 0xF, 0xF, false);
}

// 16-lane sum, replicated in all 16 lanes of each row. Pure-DPP (no LDS pipe).
__device__ __forceinline__ float sum16(float v) {
    int b;
    b = __builtin_amdgcn_update_dpp(0, __float_as_int(v), 0xB1, 0xF, 0xF, false);  // quad_perm xor1
    v += __int_as_float(b);
    b = __builtin_amdgcn_update_dpp(0, __float_as_int(v), 0x4E, 0xF, 0xF, false);  // quad_perm xor2
    v += __int_as_float(b);
    b = __builtin_amdgcn_update_dpp(0, __float_as_int(v), 0x141, 0xF, 0xF, false); // row_half_mirror
    v += __int_as_float(b);
    b = __builtin_amdgcn_update_dpp(0, __float_as_int(v), 0x140, 0xF, 0xF, false); // row_mirror
    v += __int_as_float(b);
    return v;
}

// ---------------- A1: per-(cloud,part) histogram, no global atomics -----------------
__global__ __launch_bounds__(256) void count_kernel(
    const float* __restrict__ x, const float* __restrict__ y,
    unsigned int* __restrict__ cellcnt) {

    __shared__ unsigned int h[NCELL];
    const int tid   = threadIdx.x;
    const int cloud = blockIdx.x >> 2;
    const int part  = blockIdx.x & 3;
    const float* __restrict__ src = (cloud < 2 ? x : y) + (size_t)(cloud & 1) * NPTS * 3;

    for (int i = tid; i < NCELL; i += 256) h[i] = 0;
    __syncthreads();
#pragma unroll
    for (int k = 0; k < 8; ++k) {
        int p = (part << 11) | (k << 8) | tid;
        atomicAdd(&h[mortonCell(src[3 * p], src[3 * p + 1], src[3 * p + 2])], 1u);
    }
    __syncthreads();
    unsigned int* cc = cellcnt + (cloud * NPART + part) * NCELL;
    for (int i = tid; i < NCELL; i += 256) cc[i] = h[i];
}

// ---------------- A2: per-cloud scan over (cell, part) in place ---------------------
__global__ __launch_bounds__(1024) void scan_kernel(unsigned int* __restrict__ cellcnt) {
    __shared__ unsigned int scanbuf[1024];
    const int tid = threadIdx.x;
    unsigned int* cc = cellcnt + blockIdx.x * (NPART * NCELL);   // [part][cell]

    unsigned int v[NPART][4], csum[4];
    unsigned int ssum = 0;
#pragma unroll
    for (int j = 0; j < 4; ++j) {
        int cell = 4 * tid + j;
        unsigned int s = 0;
#pragma unroll
        for (int p = 0; p < NPART; ++p) { v[p][j] = cc[p * NCELL + cell]; s += v[p][j]; }
        csum[j] = s; ssum += s;
    }
    scanbuf[tid] = ssum;
    __syncthreads();
    for (int d = 1; d < 1024; d <<= 1) {
        unsigned int a = scanbuf[tid];
        unsigned int w = (tid >= d) ? scanbuf[tid - d] : 0;
        __syncthreads();
        scanbuf[tid] = a + w;
        __syncthreads();
    }
    unsigned int run = scanbuf[tid] - ssum;
#pragma unroll
    for (int j = 0; j < 4; ++j) {
        int cell = 4 * tid + j;
        unsigned int pr = run;
#pragma unroll
        for (int p = 0; p < NPART; ++p) { cc[p * NCELL + cell] = pr; pr += v[p][j]; }
        run += csum[j];
    }
}

// ---------------- A3: scatter via atomic ticket on [cloud][part][cell] --------------
__global__ __launch_bounds__(256) void scatter_kernel(
    const float* __restrict__ x, const float* __restrict__ y,
    unsigned int* __restrict__ cellcnt,
    float4* __restrict__ Ps, unsigned short* __restrict__ origids) {

    const int tid   = threadIdx.x;
    const int cloud = blockIdx.x >> 2;
    const int part  = blockIdx.x & 3;
    const float* __restrict__ src = (cloud < 2 ? x : y) + (size_t)(cloud & 1) * NPTS * 3;
    unsigned int* cc = cellcnt + (cloud * NPART + part) * NCELL;

#pragma unroll
    for (int k = 0; k < 8; ++k) {
        int p = (part << 11) | (k << 8) | tid;
        float px = src[3 * p], py = src[3 * p + 1], pz = src[3 * p + 2];
        int c = mortonCell(px, py, pz);
        unsigned int pos = atomicAdd(&cc[c], 1u);
        Ps[(cloud << 13) + pos] = make_float4(-2.f * px, -2.f * py, -2.f * pz,
                                              px * px + py * py + pz * pz);
        origids[(cloud << 13) + pos] = (unsigned short)p;
    }
}

// ---------------- A4: chunk AABBs, one wave per chunk -------------------------------
__global__ __launch_bounds__(256) void aabb_kernel(
    const float4* __restrict__ Ps, float* __restrict__ aabbG /* [4][6][NCHUNK] */) {

    const int tid  = threadIdx.x;
    const int lane = tid & 63;
    const int w    = (blockIdx.x << 2) | (tid >> 6);   // 0..511
    const int cloud = w >> 7;
    const int c     = w & 127;

    float4 f = Ps[(cloud << 13) | (c << 6) | lane];
    float px = -0.5f * f.x, py = -0.5f * f.y, pz = -0.5f * f.z;
    float lx = px, hx = px, ly = py, hy = py, lz = pz, hz = pz;
#pragma unroll
    for (int s = 1; s < 64; s <<= 1) {
        lx = fminf(lx, __shfl_xor(lx, s)); hx = fmaxf(hx, __shfl_xor(hx, s));
        ly = fminf(ly, __shfl_xor(ly, s)); hy = fmaxf(hy, __shfl_xor(hy, s));
        lz = fminf(lz, __shfl_xor(lz, s)); hz = fmaxf(hz, __shfl_xor(hz, s));
    }
    if (lane == 0) {
        float* ab = aabbG + cloud * (6 * NCHUNK);
        ab[0 * NCHUNK + c] = lx; ab[1 * NCHUNK + c] = hx;
        ab[2 * NCHUNK + c] = ly; ab[3 * NCHUNK + c] = hy;
        ab[4 * NCHUNK + c] = lz; ab[5 * NCHUNK + c] = hz;
    }
}

// ---------------- Kernel B: best-first kNN + covariance + eig, ONE WAVE PER BLOCK ---
__global__ __launch_bounds__(64) void knn_cov_kernel(
    const float4* __restrict__ Ps, const unsigned short* __restrict__ origids,
    const float* __restrict__ aabbG, float* __restrict__ er) {

    const int lane = threadIdx.x;
    const int wid  = blockIdx.x;           // global query id, 0..32767
    const int cloud = wid >> 13;
    const int s     = wid & (NPTS - 1);    // sorted position

    const float4* __restrict__ Pc = Ps + (cloud << 13);
    const float* __restrict__ ab = aabbG + cloud * (6 * NCHUNK);
    const float4 qp = Pc[s];
    const float sqq = qp.w;
    const float qx = -0.5f * qp.x, qy = -0.5f * qp.y, qz = -0.5f * qp.z;
    const int co = s >> 6;   // own chunk

    // --- Chunk AABB bounds: 2 chunks per lane, straight from L2 ---
    float bval[2];
#pragma unroll
    for (int g = 0; g < 2; ++g) {
        int c = (g << 6) | lane;
        float dxl = fmaxf(0.f, fmaxf(ab[c] - qx, qx - ab[NCHUNK + c]));
        float dyl = fmaxf(0.f, fmaxf(ab[2 * NCHUNK + c] - qy, qy - ab[3 * NCHUNK + c]));
        float dzl = fmaxf(0.f, fmaxf(ab[4 * NCHUNK + c] - qz, qz - ab[5 * NCHUNK + c]));
        bval[g] = dxl * dxl + dyl * dyl + dzl * dzl;
    }
    unsigned long long rem0 = ~0ull, rem1 = ~0ull;
    if (co < 64) rem0 &= ~(1ull << co); else rem1 &= ~(1ull << (co - 64));

    // dual (min, 2nd-min) reduce: key = bound-bits (low 7 mantissa dropped) | chunk id.
    auto dual_argmin = [&](unsigned long long live0, unsigned long long live1,
                           int& cidA, int& cidB, bool& hasB) {
        unsigned int k0 = ((live0 >> lane) & 1)
            ? ((__float_as_uint(bval[0]) & 0xFFFFFF80u) | (unsigned)lane) : 0xFFFFFFFFu;
        unsigned int k1 = ((live1 >> lane) & 1)
            ? ((__float_as_uint(bval[1]) & 0xFFFFFF80u) | (unsigned)(64 + lane)) : 0xFFFFFFFFu;
        unsigned int a = min(k0, k1), b = max(k0, k1);
#pragma unroll
        for (int w = 1; w < 64; w <<= 1) {
            unsigned int oa = __shfl_xor(a, w);
            unsigned int ob = __shfl_xor(b, w);
            unsigned int mn = min(a, oa), mx = max(a, oa);
            unsigned int c2 = (a < oa) ? b : ob;
            a = mn; b = min(mx, c2);
        }
        cidA = (int)(a & 127u);
        hasB = (b != 0xFFFFFFFFu); cidB = (int)(b & 127u);
    };
    auto clear_rem = [&](int cid) {
        if (cid < 64) rem0 &= ~(1ull << cid); else rem1 &= ~(1ull << (cid - 64));
    };
    auto bound_of = [&](int cid) {
        return __int_as_float(__builtin_amdgcn_readlane(
            __float_as_int(bval[cid >> 6]), cid & 63));
    };

    // --- Preload the two nearest non-own chunks (loads in flight during seed) ---
    int pA, pB; bool hB;
    dual_argmin(rem0, rem1, pA, pB, hB);
    clear_rem(pA); clear_rem(pB);
    float4 pfA = Pc[(pA << 6) | lane];
    float4 pfB = Pc[(pB << 6) | lane];

    // --- Seed: 64-lane bitonic sort of own chunk (includes self) ---
    float valV, thr;
    int   idxV;
    {
        int pos = (co << 6) | lane;
        float4 f = Pc[pos];
        float k = fmaf(qx, f.x, fmaf(qy, f.y, fmaf(qz, f.z, sqq + f.w)));
        int p = pos;
#pragma unroll
        for (int size = 2; size <= 64; size <<= 1) {
#pragma unroll
            for (int stride = size >> 1; stride >= 1; stride >>= 1) {
                float ok = __shfl_xor(k, stride);
                int   op = __shfl_xor(p, stride);
                bool up = ((lane & size) == 0);
                bool lower = ((lane & stride) == 0);
                bool want_min = (up == lower);
                bool take = want_min ? (ok < k) : (ok > k);
                k = take ? ok : k;
                p = take ? op : p;
            }
        }
        valV = __shfl(k, lane & 15);
        idxV = __shfl(p, lane & 15);
        thr  = __shfl(k, 15);
    }

    // Process one loaded chunk: ballot + waterfall insert + thr update.
    auto process = [&](float4 f, int cid) {
        float d2 = fmaf(qx, f.x, fmaf(qy, f.y, fmaf(qz, f.z, sqq + f.w)));
        unsigned long long m = __ballot(d2 < thr);
        if (m) {
            do {
                int li = __builtin_ctzll(m); m &= m - 1;
                float sv = __int_as_float(
                    __builtin_amdgcn_readlane(__float_as_int(d2), li));
                int sj = (cid << 6) | li;
                float pv = dpp_prev_f(valV);
                int   pi = dpp_prev_i(idxV);
                bool keep  = (valV <= sv);
                bool fromv = ((lane & 15) == 0) || (pv <= sv);
                float nv = keep ? valV : (fromv ? sv : pv);
                int   ni = keep ? idxV : (fromv ? sj : pi);
                valV = nv; idxV = ni;
            } while (m);
            thr = __int_as_float(__builtin_amdgcn_readlane(__float_as_int(valV), 15));
        }
    };

    // consume preloads (clearing when bound >= thr is safe: bound >= thr_now >= thr_final)
    if (bound_of(pA) < thr) process(pfA, pA);
    if (bound_of(pB) < thr) process(pfB, pB);

    // --- Best-first rounds, popping two chunks per round; cheap path when <=2 live --
    for (;;) {
        unsigned long long live0 = rem0 & __ballot(bval[0] < thr);
        unsigned long long live1 = rem1 & __ballot(bval[1] < thr);
        if (!(live0 | live1)) break;

        int cidA, cidB; bool hasB;
        if (__popcll(live0) + __popcll(live1) <= 2) {
            // order irrelevant: both must be scanned anyway
            if (live0) { cidA = __builtin_ctzll(live0); live0 &= live0 - 1; }
            else       { cidA = 64 + __builtin_ctzll(live1); live1 &= live1 - 1; }
            if (live0)      { cidB = __builtin_ctzll(live0); hasB = true; }
            else if (live1) { cidB = 64 + __builtin_ctzll(live1); hasB = true; }
            else hasB = false;
        } else {
            dual_argmin(live0, live1, cidA, cidB, hasB);
        }
        clear_rem(cidA);
        if (hasB) clear_rem(cidB);

        float4 fA = Pc[(cidA << 6) | lane];
        float4 fB;
        if (hasB) fB = Pc[(cidB << 6) | lane];

        process(fA, cidA);
        if (hasB && bound_of(cidB) < thr) process(fB, cidB);
    }

    // --- Covariance of the 16 selected (replicated across all lanes after sum16) ---
    float4 nf = Pc[idxV];
    float nx = -0.5f * nf.x, ny = -0.5f * nf.y, nz = -0.5f * nf.z;

    const float invk = 1.0f / KNN;
    float mx = sum16(nx) * invk;
    float my = sum16(ny) * invk;
    float mz = sum16(nz) * invk;

    float dx = nx - mx, dy = ny - my, dz = nz - mz;
    float c00 = sum16(dx * dx) * invk, c01 = sum16(dx * dy) * invk, c02 = sum16(dx * dz) * invk;
    float c11 = sum16(dy * dy) * invk, c12 = sum16(dy * dz) * invk, c22 = sum16(dz * dz) * invk;

    // --- Eigen-ratio (fp64 closed form), computed redundantly on all lanes ---
    double a00 = c00, a01 = c01, a02 = c02, a11 = c11, a12 = c12, a22 = c22;
    double qm = (a00 + a11 + a22) * (1.0 / 3.0);
    double p1 = a01 * a01 + a02 * a02 + a12 * a12;
    double b00 = a00 - qm, b11 = a11 - qm, b22 = a22 - qm;
    double p2 = b00 * b00 + b11 * b11 + b22 * b22 + 2.0 * p1;

    double ratio;
    if (p2 <= 0.0) {
        ratio = 1.0;
    } else {
        double p = sqrt(p2 * (1.0 / 6.0));
        double inv = 1.0 / p;
        double m00 = b00 * inv, m11 = b11 * inv, m22 = b22 * inv;
        double m01 = a01 * inv, m02 = a02 * inv, m12 = a12 * inv;
        double detB = m00 * (m11 * m22 - m12 * m12)
                    - m01 * (m01 * m22 - m12 * m02)
                    + m02 * (m01 * m12 - m11 * m02);
        double r = 0.5 * detB;
        r = fmin(1.0, fmax(-1.0, r));
        double phi = acos(r) * (1.0 / 3.0);
        double e1 = qm + 2.0 * p * cos(phi);
        double e3 = qm + 2.0 * p * cos(phi + 2.0943951023931953);
        double e2 = 3.0 * qm - e1 - e3;
        ratio = e1 / e2;
    }

    if (lane == 0) {
        int orig = origids[(cloud << 13) + s];
        er[(cloud << 13) + orig] = (float)ratio;
    }
}

// ---------------- final: single-block reduce over er --------------------------------
__global__ __launch_bounds__(1024) void final_kernel(const float* __restrict__ er,
                                                     float* __restrict__ out) {
    __shared__ double sb[1024];
    double acc = 0.0;
    const int total = 2 * NPTS;   // 16384 (b,n) pairs
    for (int i = threadIdx.x; i < total; i += 1024) {
        double d = (double)er[i] - (double)er[total + i];
        acc += d * d;
    }
    sb[threadIdx.x] = acc;
    __syncthreads();
    for (int s2 = 512; s2 > 0; s2 >>= 1) {
        if (threadIdx.x < s2) sb[threadIdx.x] += sb[threadIdx.x + s2];
        __syncthreads();
    }
    if (threadIdx.x == 0) out[0] = (float)(sb[0] / (double)total);
}

extern "C" void kernel_launch(void* const* d_in, const int* in_sizes, int n_in,
                              void* d_out, int out_size, void* d_ws, size_t ws_size,
                              hipStream_t stream) {
    const float* x = (const float*)d_in[0];
    const float* y = (const float*)d_in[1];
    char* ws = (char*)d_ws;

    float4*         Ps      = (float4*)(ws);                    // 524288 B
    unsigned short* origids = (unsigned short*)(ws + 524288);   // 65536 B
    float*          aabbG   = (float*)(ws + 589824);            // 12288 B
    float*          er      = (float*)(ws + 602112);            // 131072 B
    unsigned int*   cellcnt = (unsigned int*)(ws + 733184);     // 262144 B
    float*          out     = (float*)d_out;

    count_kernel<<<4 * NPART, 256, 0, stream>>>(x, y, cellcnt);
    scan_kernel<<<4, 1024, 0, stream>>>(cellcnt);
    scatter_kernel<<<4 * NPART, 256, 0, stream>>>(x, y, cellcnt, Ps, origids);
    aabb_kernel<<<128, 256, 0, stream>>>(Ps, aabbG);
    knn_cov_kernel<<<4 * NPTS, 64, 0, stream>>>(Ps, origids, aabbG, er);
    final_kernel<<<1, 1024, 0, stream>>>(er, out);
}

// Round 10
// 90.079 us; speedup vs baseline: 1.1357x; 1.1357x over previous
//
#include <hip/hip_runtime.h>
#include <hip/hip_bf16.h>
#include <math.h>

#define NPTS   8192
#define KNN    16
#define G      16
#define NCELL  (G * G * G)
#define NCHUNK 128              // 64-point chunks per cloud
#define NPART  4                // scatter partitions per cloud

// Fixed standard-normal quantile boundaries (i/16). Only affect load balance,
// never correctness.
__constant__ float c_B[17] = {
    -1e30f,
    -1.5341205f, -1.1503494f, -0.8871466f, -0.6744898f, -0.4887764f,
    -0.3186394f, -0.1573107f,  0.0f,        0.1573107f,  0.3186394f,
     0.4887764f,  0.6744898f,  0.8871466f,  1.1503494f,  1.5341205f,
     1e30f
};

__device__ __forceinline__ int cellOf(float v) {
    int c = 0;
#pragma unroll
    for (int i = 1; i <= 15; ++i) c += (v >= c_B[i]) ? 1 : 0;
    return c;
}

// spread 4 bits to positions 0,3,6,9
__device__ __forceinline__ int spread3(int v) {
    v = (v | (v << 4)) & 0x0C3;
    v = (v | (v << 2)) & 0x249;
    return v;
}

__device__ __forceinline__ int mortonCell(float px, float py, float pz) {
    return (spread3(cellOf(px)) << 2) | (spread3(cellOf(py)) << 1) | spread3(cellOf(pz));
}

// prev-lane within each 16-lane row (DPP row_shr:1); row-head lanes masked by caller.
__device__ __forceinline__ float dpp_prev_f(float v) {
    int r = __builtin_amdgcn_update_dpp(0, __float_as_int(v), 0x111, 0xF, 0xF, false);
    return __int_as_float(r);
}
__device__ __forceinline__ int dpp_prev_i(int v) {
    return __builtin_amdgcn_update_dpp(0, v, 0x111, 0xF, 0xF, false);
}

// 16-lane sum, replicated in all 16 lanes of each row. Pure-DPP (no LDS pipe).
__device__ __forceinline__ float sum16(float v) {
    int b;
    b = __builtin_amdgcn_update_dpp(0, __float_as_int(v), 0xB1, 0xF, 0xF, false);  // quad_perm xor1
    v += __int_as_float(b);
    b = __builtin_amdgcn_update_dpp(0, __float_as_int(v), 0x4E, 0xF, 0xF, false);  // quad_perm xor2
    v += __int_as_float(b);
    b = __builtin_amdgcn_update_dpp(0, __float_as_int(v), 0x141, 0xF, 0xF, false); // row_half_mirror
    v += __int_as_float(b);
    b = __builtin_amdgcn_update_dpp(0, __float_as_int(v), 0x140, 0xF, 0xF, false); // row_mirror
    v += __int_as_float(b);
    return v;
}

// ---------------- A1: fused count + scan, one block per cloud -----------------------
__global__ __launch_bounds__(1024) void countscan_kernel(
    const float* __restrict__ x, const float* __restrict__ y,
    unsigned int* __restrict__ cellcnt /* [4][NCELL] exclusive starts */) {

    __shared__ unsigned int h[NCELL];
    __shared__ unsigned int scanbuf[1024];
    const int tid   = threadIdx.x;
    const int cloud = blockIdx.x;
    const float* __restrict__ src = (cloud < 2 ? x : y) + (size_t)(cloud & 1) * NPTS * 3;

    for (int i = tid; i < NCELL; i += 1024) h[i] = 0;
    __syncthreads();
#pragma unroll
    for (int k = 0; k < 8; ++k) {
        int p = (k << 10) | tid;
        atomicAdd(&h[mortonCell(src[3 * p], src[3 * p + 1], src[3 * p + 2])], 1u);
    }
    __syncthreads();

    // thread t owns cells 4t..4t+3
    unsigned int c0 = h[4 * tid], c1 = h[4 * tid + 1];
    unsigned int c2 = h[4 * tid + 2], c3 = h[4 * tid + 3];
    unsigned int ssum = c0 + c1 + c2 + c3;
    scanbuf[tid] = ssum;
    __syncthreads();
    for (int d = 1; d < 1024; d <<= 1) {
        unsigned int a = scanbuf[tid];
        unsigned int w = (tid >= d) ? scanbuf[tid - d] : 0;
        __syncthreads();
        scanbuf[tid] = a + w;
        __syncthreads();
    }
    unsigned int excl = scanbuf[tid] - ssum;
    unsigned int* cc = cellcnt + cloud * NCELL;
    cc[4 * tid]     = excl;
    cc[4 * tid + 1] = excl + c0;
    cc[4 * tid + 2] = excl + c0 + c1;
    cc[4 * tid + 3] = excl + c0 + c1 + c2;
}

// ---------------- A2: scatter via atomic ticket on [cloud][cell] --------------------
__global__ __launch_bounds__(256) void scatter_kernel(
    const float* __restrict__ x, const float* __restrict__ y,
    unsigned int* __restrict__ cellcnt,
    float4* __restrict__ Ps, unsigned short* __restrict__ origids) {

    const int tid   = threadIdx.x;
    const int cloud = blockIdx.x >> 2;
    const int part  = blockIdx.x & 3;
    const float* __restrict__ src = (cloud < 2 ? x : y) + (size_t)(cloud & 1) * NPTS * 3;
    unsigned int* cc = cellcnt + cloud * NCELL;

#pragma unroll
    for (int k = 0; k < 8; ++k) {
        int p = (part << 11) | (k << 8) | tid;
        float px = src[3 * p], py = src[3 * p + 1], pz = src[3 * p + 2];
        int c = mortonCell(px, py, pz);
        unsigned int pos = atomicAdd(&cc[c], 1u);
        Ps[(cloud << 13) + pos] = make_float4(-2.f * px, -2.f * py, -2.f * pz,
                                              px * px + py * py + pz * pz);
        origids[(cloud << 13) + pos] = (unsigned short)p;
    }
}

// ---------------- A3: chunk AABBs, one wave per chunk -------------------------------
__global__ __launch_bounds__(256) void aabb_kernel(
    const float4* __restrict__ Ps, float* __restrict__ aabbG /* [4][6][NCHUNK] */) {

    const int tid  = threadIdx.x;
    const int lane = tid & 63;
    const int w    = (blockIdx.x << 2) | (tid >> 6);   // 0..511
    const int cloud = w >> 7;
    const int c     = w & 127;

    float4 f = Ps[(cloud << 13) | (c << 6) | lane];
    float px = -0.5f * f.x, py = -0.5f * f.y, pz = -0.5f * f.z;
    float lx = px, hx = px, ly = py, hy = py, lz = pz, hz = pz;
#pragma unroll
    for (int s = 1; s < 64; s <<= 1) {
        lx = fminf(lx, __shfl_xor(lx, s)); hx = fmaxf(hx, __shfl_xor(hx, s));
        ly = fminf(ly, __shfl_xor(ly, s)); hy = fmaxf(hy, __shfl_xor(hy, s));
        lz = fminf(lz, __shfl_xor(lz, s)); hz = fmaxf(hz, __shfl_xor(hz, s));
    }
    if (lane == 0) {
        float* ab = aabbG + cloud * (6 * NCHUNK);
        ab[0 * NCHUNK + c] = lx; ab[1 * NCHUNK + c] = hx;
        ab[2 * NCHUNK + c] = ly; ab[3 * NCHUNK + c] = hy;
        ab[4 * NCHUNK + c] = lz; ab[5 * NCHUNK + c] = hz;
    }
}

// ---------------- Kernel B: best-first kNN + covariance, ONE WAVE PER BLOCK ---------
__global__ __launch_bounds__(64) void knn_cov_kernel(
    const float4* __restrict__ Ps, const unsigned short* __restrict__ origids,
    const float* __restrict__ aabbG, float* __restrict__ cov) {

    const int lane = threadIdx.x;
    const int wid  = blockIdx.x;           // global query id, 0..32767
    const int cloud = wid >> 13;
    const int s     = wid & (NPTS - 1);    // sorted position

    const float4* __restrict__ Pc = Ps + (cloud << 13);
    const float* __restrict__ ab = aabbG + cloud * (6 * NCHUNK);
    const float4 qp = Pc[s];
    const float sqq = qp.w;
    const float qx = -0.5f * qp.x, qy = -0.5f * qp.y, qz = -0.5f * qp.z;
    const int co = s >> 6;   // own chunk

    // --- Chunk AABB bounds: 2 chunks per lane, straight from L2 ---
    float bval[2];
#pragma unroll
    for (int g = 0; g < 2; ++g) {
        int c = (g << 6) | lane;
        float dxl = fmaxf(0.f, fmaxf(ab[c] - qx, qx - ab[NCHUNK + c]));
        float dyl = fmaxf(0.f, fmaxf(ab[2 * NCHUNK + c] - qy, qy - ab[3 * NCHUNK + c]));
        float dzl = fmaxf(0.f, fmaxf(ab[4 * NCHUNK + c] - qz, qz - ab[5 * NCHUNK + c]));
        bval[g] = dxl * dxl + dyl * dyl + dzl * dzl;
    }
    unsigned long long rem0 = ~0ull, rem1 = ~0ull;
    if (co < 64) rem0 &= ~(1ull << co); else rem1 &= ~(1ull << (co - 64));

    // dual (min, 2nd-min) reduce: key = bound-bits (low 7 mantissa dropped) | chunk id.
    auto dual_argmin = [&](unsigned long long live0, unsigned long long live1,
                           int& cidA, int& cidB, bool& hasB) {
        unsigned int k0 = ((live0 >> lane) & 1)
            ? ((__float_as_uint(bval[0]) & 0xFFFFFF80u) | (unsigned)lane) : 0xFFFFFFFFu;
        unsigned int k1 = ((live1 >> lane) & 1)
            ? ((__float_as_uint(bval[1]) & 0xFFFFFF80u) | (unsigned)(64 + lane)) : 0xFFFFFFFFu;
        unsigned int a = min(k0, k1), b = max(k0, k1);
#pragma unroll
        for (int w = 1; w < 64; w <<= 1) {
            unsigned int oa = __shfl_xor(a, w);
            unsigned int ob = __shfl_xor(b, w);
            unsigned int mn = min(a, oa), mx = max(a, oa);
            unsigned int c2 = (a < oa) ? b : ob;
            a = mn; b = min(mx, c2);
        }
        cidA = (int)(a & 127u);
        hasB = (b != 0xFFFFFFFFu); cidB = (int)(b & 127u);
    };
    auto clear_rem = [&](int cid) {
        if (cid < 64) rem0 &= ~(1ull << cid); else rem1 &= ~(1ull << (cid - 64));
    };
    auto bound_of = [&](int cid) {
        return __int_as_float(__builtin_amdgcn_readlane(
            __float_as_int(bval[cid >> 6]), cid & 63));
    };

    // --- Preload the two nearest non-own chunks (loads in flight during seed) ---
    int pA, pB; bool hB;
    dual_argmin(rem0, rem1, pA, pB, hB);
    clear_rem(pA); clear_rem(pB);
    float4 pfA = Pc[(pA << 6) | lane];
    float4 pfB = Pc[(pB << 6) | lane];

    // --- Seed: 64-lane bitonic sort of own chunk (includes self) ---
    float valV, thr;
    int   idxV;
    {
        int pos = (co << 6) | lane;
        float4 f = Pc[pos];
        float k = fmaf(qx, f.x, fmaf(qy, f.y, fmaf(qz, f.z, sqq + f.w)));
        int p = pos;
#pragma unroll
        for (int size = 2; size <= 64; size <<= 1) {
#pragma unroll
            for (int stride = size >> 1; stride >= 1; stride >>= 1) {
                float ok = __shfl_xor(k, stride);
                int   op = __shfl_xor(p, stride);
                bool up = ((lane & size) == 0);
                bool lower = ((lane & stride) == 0);
                bool want_min = (up == lower);
                bool take = want_min ? (ok < k) : (ok > k);
                k = take ? ok : k;
                p = take ? op : p;
            }
        }
        valV = __shfl(k, lane & 15);
        idxV = __shfl(p, lane & 15);
        thr  = __shfl(k, 15);
    }

    // Process one loaded chunk: ballot + waterfall insert + thr update.
    auto process = [&](float4 f, int cid) {
        float d2 = fmaf(qx, f.x, fmaf(qy, f.y, fmaf(qz, f.z, sqq + f.w)));
        unsigned long long m = __ballot(d2 < thr);
        if (m) {
            do {
                int li = __builtin_ctzll(m); m &= m - 1;
                float sv = __int_as_float(
                    __builtin_amdgcn_readlane(__float_as_int(d2), li));
                int sj = (cid << 6) | li;
                float pv = dpp_prev_f(valV);
                int   pi = dpp_prev_i(idxV);
                bool keep  = (valV <= sv);
                bool fromv = ((lane & 15) == 0) || (pv <= sv);
                float nv = keep ? valV : (fromv ? sv : pv);
                int   ni = keep ? idxV : (fromv ? sj : pi);
                valV = nv; idxV = ni;
            } while (m);
            thr = __int_as_float(__builtin_amdgcn_readlane(__float_as_int(valV), 15));
        }
    };

    // consume preloads (clearing when bound >= thr is safe: bound >= thr_now >= thr_final)
    if (bound_of(pA) < thr) process(pfA, pA);
    if (bound_of(pB) < thr) process(pfB, pB);

    // --- Best-first rounds, popping two chunks per round; cheap path when <=2 live --
    for (;;) {
        unsigned long long live0 = rem0 & __ballot(bval[0] < thr);
        unsigned long long live1 = rem1 & __ballot(bval[1] < thr);
        if (!(live0 | live1)) break;

        int cidA, cidB; bool hasB;
        if (__popcll(live0) + __popcll(live1) <= 2) {
            if (live0) { cidA = __builtin_ctzll(live0); live0 &= live0 - 1; }
            else       { cidA = 64 + __builtin_ctzll(live1); live1 &= live1 - 1; }
            if (live0)      { cidB = __builtin_ctzll(live0); hasB = true; }
            else if (live1) { cidB = 64 + __builtin_ctzll(live1); hasB = true; }
            else hasB = false;
        } else {
            dual_argmin(live0, live1, cidA, cidB, hasB);
        }
        clear_rem(cidA);
        if (hasB) clear_rem(cidB);

        float4 fA = Pc[(cidA << 6) | lane];
        float4 fB;
        if (hasB) fB = Pc[(cidB << 6) | lane];

        process(fA, cidA);
        if (hasB && bound_of(cidB) < thr) process(fB, cidB);
    }

    // --- Covariance of the 16 selected (replicated across all lanes after sum16) ---
    float4 nf = Pc[idxV];
    float nx = -0.5f * nf.x, ny = -0.5f * nf.y, nz = -0.5f * nf.z;

    const float invk = 1.0f / KNN;
    float mx = sum16(nx) * invk;
    float my = sum16(ny) * invk;
    float mz = sum16(nz) * invk;

    float dx = nx - mx, dy = ny - my, dz = nz - mz;
    float c00 = sum16(dx * dx) * invk, c01 = sum16(dx * dy) * invk, c02 = sum16(dx * dz) * invk;
    float c11 = sum16(dy * dy) * invk, c12 = sum16(dy * dz) * invk, c22 = sum16(dz * dz) * invk;

    if (lane == 0) {
        int orig = origids[(cloud << 13) + s];
        float* cp = cov + ((size_t)(cloud << 13) + orig) * 6;   // 24B stride, 8B aligned
        *(float2*)(cp)     = make_float2(c00, c01);
        *(float2*)(cp + 2) = make_float2(c02, c11);
        *(float2*)(cp + 4) = make_float2(c12, c22);
    }
}

// ---------------- eig (thread-parallel) + partial reduce ----------------------------
__device__ double eig_ratio(const float* __restrict__ cp) {
    double a00 = cp[0], a01 = cp[1], a02 = cp[2];
    double a11 = cp[3], a12 = cp[4], a22 = cp[5];

    double qm = (a00 + a11 + a22) * (1.0 / 3.0);
    double p1 = a01 * a01 + a02 * a02 + a12 * a12;
    double b00 = a00 - qm, b11 = a11 - qm, b22 = a22 - qm;
    double p2 = b00 * b00 + b11 * b11 + b22 * b22 + 2.0 * p1;

    if (p2 <= 0.0) return 1.0;
    double p = sqrt(p2 * (1.0 / 6.0));
    double inv = 1.0 / p;
    double m00 = b00 * inv, m11 = b11 * inv, m22 = b22 * inv;
    double m01 = a01 * inv, m02 = a02 * inv, m12 = a12 * inv;
    double detB = m00 * (m11 * m22 - m12 * m12)
                - m01 * (m01 * m22 - m12 * m02)
                + m02 * (m01 * m12 - m11 * m02);
    double r = 0.5 * detB;
    r = fmin(1.0, fmax(-1.0, r));
    double phi = acos(r) * (1.0 / 3.0);
    double e1 = qm + 2.0 * p * cos(phi);
    double e3 = qm + 2.0 * p * cos(phi + 2.0943951023931953);
    double e2 = 3.0 * qm - e1 - e3;
    return e1 / e2;
}

__global__ __launch_bounds__(256) void eigred_kernel(const float* __restrict__ cov,
                                                     double* __restrict__ partial) {
    __shared__ double sb[256];
    const int i = blockIdx.x * 256 + threadIdx.x;   // 0..16383 (x-side pairs)
    double r1 = eig_ratio(cov + (size_t)i * 6);
    double r2 = eig_ratio(cov + (size_t)(2 * NPTS + i) * 6);
    double d = r1 - r2;
    sb[threadIdx.x] = d * d;
    __syncthreads();
    for (int s2 = 128; s2 > 0; s2 >>= 1) {
        if (threadIdx.x < s2) sb[threadIdx.x] += sb[threadIdx.x + s2];
        __syncthreads();
    }
    if (threadIdx.x == 0) partial[blockIdx.x] = sb[0];
}

__global__ __launch_bounds__(64) void final_kernel(const double* __restrict__ partial,
                                                   float* __restrict__ out) {
    double v = partial[threadIdx.x];
#pragma unroll
    for (int w = 1; w < 64; w <<= 1) v += __shfl_xor(v, w);
    if (threadIdx.x == 0) out[0] = (float)(v / (double)(2 * NPTS));
}

extern "C" void kernel_launch(void* const* d_in, const int* in_sizes, int n_in,
                              void* d_out, int out_size, void* d_ws, size_t ws_size,
                              hipStream_t stream) {
    const float* x = (const float*)d_in[0];
    const float* y = (const float*)d_in[1];
    char* ws = (char*)d_ws;

    float4*         Ps      = (float4*)(ws);                    // 524288 B
    unsigned short* origids = (unsigned short*)(ws + 524288);   // 65536 B
    float*          aabbG   = (float*)(ws + 589824);            // 12288 B
    float*          cov     = (float*)(ws + 602112);            // 786432 B
    unsigned int*   cellcnt = (unsigned int*)(ws + 1388544);    // 65536 B
    double*         partial = (double*)(ws + 1454080);          // 512 B
    float*          out     = (float*)d_out;

    countscan_kernel<<<4, 1024, 0, stream>>>(x, y, cellcnt);
    scatter_kernel<<<4 * NPART, 256, 0, stream>>>(x, y, cellcnt, Ps, origids);
    aabb_kernel<<<128, 256, 0, stream>>>(Ps, aabbG);
    knn_cov_kernel<<<4 * NPTS, 64, 0, stream>>>(Ps, origids, aabbG, cov);
    eigred_kernel<<<64, 256, 0, stream>>>(cov, partial);
    final_kernel<<<1, 64, 0, stream>>>(partial, out);
}